// Round 1
// baseline (12572.516 us; speedup 1.0000x reference)
//
#include <hip/hip_runtime.h>
#include <math.h>

// Problem constants (from reference)
constexpr int kDIS = 3000;
constexpr int kSNO = 6000;
constexpr int kN   = 9000;   // DIS + SNO
constexpr int kE   = 288000;
constexpr int kF1  = 512, kF2 = 256, kF3 = 128;

// ---------------------------------------------------------------------------
// Edge preprocessing
// ---------------------------------------------------------------------------
__global__ void k_init_deg(float* __restrict__ deg) {
    int i = blockIdx.x * blockDim.x + threadIdx.x;
    if (i < kN) deg[i] = 1.0f;   // self-loop weight
}

__global__ void k_gather(const float* __restrict__ adj, const int* __restrict__ src,
                         const int* __restrict__ dst, float* __restrict__ wE,
                         float* __restrict__ deg) {
    int e = blockIdx.x * blockDim.x + threadIdx.x;
    if (e >= kE) return;
    int s = src[e], d = dst[e];
    float w = adj[(size_t)s * kN + d];
    wE[e] = w;
    atomicAdd(&deg[d], w);
}

__global__ void k_dinv(const float* __restrict__ deg, float* __restrict__ dinv) {
    int i = blockIdx.x * blockDim.x + threadIdx.x;
    if (i < kN) {
        float d = deg[i];
        dinv[i] = d > 0.f ? 1.0f / sqrtf(d) : 0.f;
    }
}

__global__ void k_edgenorm(float* __restrict__ wE, const int* __restrict__ src,
                           const int* __restrict__ dst, const float* __restrict__ dinv) {
    int e = blockIdx.x * blockDim.x + threadIdx.x;
    if (e >= kE) return;
    wE[e] = dinv[src[e]] * wE[e] * dinv[dst[e]];
}

// ---------------------------------------------------------------------------
// GCN aggregation pieces
// ---------------------------------------------------------------------------
// Hout[i] = Htmp[i] * dinv[i]^2   (self-loop contribution, also zero-inits Hout)
__global__ void k_selfloop(const float* __restrict__ Htmp, const float* __restrict__ dinv,
                           float* __restrict__ Hout, int F4) {
    int idx = blockIdx.x * blockDim.x + threadIdx.x;
    int tot = kN * F4;
    if (idx >= tot) return;
    int r = idx / F4;
    float di = dinv[r];
    float sl = di * di;
    float4 h = ((const float4*)Htmp)[idx];
    float4 o;
    o.x = h.x * sl; o.y = h.y * sl; o.z = h.z * sl; o.w = h.w * sl;
    ((float4*)Hout)[idx] = o;
}

__global__ void k_scatter(const float* __restrict__ Htmp, float* __restrict__ Hout,
                          const int* __restrict__ src, const int* __restrict__ dst,
                          const float* __restrict__ nrm, int F4) {
    int idx = blockIdx.x * blockDim.x + threadIdx.x;
    int tot = kE * F4;
    if (idx >= tot) return;
    int e = idx / F4;          // F4 is a power of two -> cheap
    int q = idx - e * F4;
    float w = nrm[e];
    const float4 h = ((const float4*)(Htmp + (size_t)src[e] * F4 * 4))[q];
    float* o = Hout + (size_t)dst[e] * F4 * 4 + q * 4;
    atomicAdd(o + 0, h.x * w);
    atomicAdd(o + 1, h.y * w);
    atomicAdd(o + 2, h.z * w);
    atomicAdd(o + 3, h.w * w);
}

__global__ void k_bias_relu(float* __restrict__ H, const float* __restrict__ b, int F4) {
    int idx = blockIdx.x * blockDim.x + threadIdx.x;
    int tot = kN * F4;
    if (idx >= tot) return;
    int q = idx % F4;
    float4 v = ((float4*)H)[idx];
    const float4 bb = ((const float4*)b)[q];
    v.x = fmaxf(v.x + bb.x, 0.f);
    v.y = fmaxf(v.y + bb.y, 0.f);
    v.z = fmaxf(v.z + bb.z, 0.f);
    v.w = fmaxf(v.w + bb.w, 0.f);
    ((float4*)H)[idx] = v;
}

// ---------------------------------------------------------------------------
// Tiled fp32 GEMM.  C[M,N] = A[M,K] @ B  (B row-major [K,N] if !TRANSB,
// else B row-major [N,K] used as B^T).
// ---------------------------------------------------------------------------
template<int BM, int BN, int BK, int TM, int TN, bool TRANSB>
__global__ __launch_bounds__(256) void k_sgemm(const float* __restrict__ A,
                                               const float* __restrict__ B,
                                               float* __restrict__ C,
                                               int M, int N, int K) {
    constexpr int TX = BN / TN, TY = BM / TM;
    static_assert(TX * TY == 256, "256 threads");
    __shared__ float As[BK][BM + 4];
    __shared__ float Bs[BK][BN + 4];
    const int tid = threadIdx.x;
    const int bm = blockIdx.y * BM, bn = blockIdx.x * BN;
    const int tx = tid % TX, ty = tid / TX;
    float acc[TM][TN] = {};
    const int nk = (K + BK - 1) / BK;
    constexpr int LA = BM * BK / (4 * 256);
    constexpr int LB = BN * BK / (4 * 256);

    for (int t = 0; t < nk; ++t) {
        int k0 = t * BK;
        // --- A tile (BM x BK), stored transposed As[k][m]
        #pragma unroll
        for (int i = 0; i < LA; ++i) {
            int idx = tid + i * 256;
            int r = idx / (BK / 4), c4 = idx % (BK / 4);
            int gr = bm + r, gk = k0 + c4 * 4;
            float4 v = make_float4(0.f, 0.f, 0.f, 0.f);
            if (gr < M && gk < K) {
                if (gk + 3 < K) v = *(const float4*)(A + (size_t)gr * K + gk);
                else {
                    const float* p = A + (size_t)gr * K;
                    v.x = p[gk];
                    if (gk + 1 < K) v.y = p[gk + 1];
                    if (gk + 2 < K) v.z = p[gk + 2];
                }
            }
            As[c4 * 4 + 0][r] = v.x;
            As[c4 * 4 + 1][r] = v.y;
            As[c4 * 4 + 2][r] = v.z;
            As[c4 * 4 + 3][r] = v.w;
        }
        // --- B tile
        if (!TRANSB) {
            #pragma unroll
            for (int i = 0; i < LB; ++i) {
                int idx = tid + i * 256;
                int r = idx / (BN / 4), c4 = idx % (BN / 4);
                int gk = k0 + r, gn = bn + c4 * 4;
                float4 v = make_float4(0.f, 0.f, 0.f, 0.f);
                if (gk < K && gn < N) {
                    if (gn + 3 < N) v = *(const float4*)(B + (size_t)gk * N + gn);
                    else {
                        const float* p = B + (size_t)gk * N;
                        v.x = p[gn];
                        if (gn + 1 < N) v.y = p[gn + 1];
                        if (gn + 2 < N) v.z = p[gn + 2];
                    }
                }
                *(float4*)&Bs[r][c4 * 4] = v;
            }
        } else {
            #pragma unroll
            for (int i = 0; i < LB; ++i) {
                int idx = tid + i * 256;
                int r = idx / (BK / 4), c4 = idx % (BK / 4);
                int gn = bn + r, gk = k0 + c4 * 4;
                float4 v = make_float4(0.f, 0.f, 0.f, 0.f);
                if (gn < N && gk < K) {
                    if (gk + 3 < K) v = *(const float4*)(B + (size_t)gn * K + gk);
                    else {
                        const float* p = B + (size_t)gn * K;
                        v.x = p[gk];
                        if (gk + 1 < K) v.y = p[gk + 1];
                        if (gk + 2 < K) v.z = p[gk + 2];
                    }
                }
                Bs[c4 * 4 + 0][r] = v.x;
                Bs[c4 * 4 + 1][r] = v.y;
                Bs[c4 * 4 + 2][r] = v.z;
                Bs[c4 * 4 + 3][r] = v.w;
            }
        }
        __syncthreads();
        #pragma unroll
        for (int k = 0; k < BK; ++k) {
            float a[TM], b[TN];
            #pragma unroll
            for (int i = 0; i < TM; ++i) a[i] = As[k][ty * TM + i];
            #pragma unroll
            for (int j = 0; j < TN; ++j) b[j] = Bs[k][tx * TN + j];
            #pragma unroll
            for (int i = 0; i < TM; ++i)
                #pragma unroll
                for (int j = 0; j < TN; ++j)
                    acc[i][j] = fmaf(a[i], b[j], acc[i][j]);
        }
        __syncthreads();
    }
    // --- store (N is always a multiple of 4 here)
    #pragma unroll
    for (int i = 0; i < TM; ++i) {
        int gr = bm + ty * TM + i;
        if (gr >= M) continue;
        #pragma unroll
        for (int j = 0; j < TN; j += 4) {
            int gc = bn + tx * TN + j;
            if (gc < N) {
                float4 v = make_float4(acc[i][j], acc[i][j + 1], acc[i][j + 2], acc[i][j + 3]);
                *(float4*)(C + (size_t)gr * N + gc) = v;
            }
        }
    }
}

// ---------------------------------------------------------------------------
// GIP kernel pieces
// ---------------------------------------------------------------------------
__global__ __launch_bounds__(256) void k_rowminmax(const float* __restrict__ H,
                                                   float* __restrict__ Yn, int F) {
    int r = blockIdx.x;
    const float* row = H + (size_t)r * F;
    float mn = INFINITY, mx = -INFINITY;
    for (int f = threadIdx.x; f < F; f += 256) {
        float v = row[f];
        mn = fminf(mn, v);
        mx = fmaxf(mx, v);
    }
    for (int o = 32; o; o >>= 1) {
        mn = fminf(mn, __shfl_xor(mn, o));
        mx = fmaxf(mx, __shfl_xor(mx, o));
    }
    __shared__ float smn[4], smx[4];
    int w = threadIdx.x >> 6;
    if ((threadIdx.x & 63) == 0) { smn[w] = mn; smx[w] = mx; }
    __syncthreads();
    mn = fminf(fminf(smn[0], smn[1]), fminf(smn[2], smn[3]));
    mx = fmaxf(fmaxf(smx[0], smx[1]), fmaxf(smx[2], smx[3]));
    float rng = mx - mn;
    if (rng == 0.f) rng = 1.f;
    for (int f = threadIdx.x; f < F; f += 256)
        Yn[(size_t)r * F + f] = (row[f] - mn) / rng;
}

__global__ void k_scal_init(float* __restrict__ meansum, unsigned* __restrict__ minbits) {
    if (threadIdx.x == 0 && blockIdx.x == 0) {
        *meansum = 0.f;
        *minbits = 0x7f800000u;   // +inf
    }
}

__global__ __launch_bounds__(256) void k_diag_mean(const float* __restrict__ Kb,
                                                   float* __restrict__ diagv,
                                                   float* __restrict__ meansum, int n) {
    float s = 0.f;
    for (int i = blockIdx.x * blockDim.x + threadIdx.x; i < n; i += gridDim.x * blockDim.x) {
        float d = Kb[(size_t)i * n + i];
        diagv[i] = d;
        s += d;
    }
    for (int o = 32; o; o >>= 1) s += __shfl_xor(s, o);
    __shared__ float sw[4];
    if ((threadIdx.x & 63) == 0) sw[threadIdx.x >> 6] = s;
    __syncthreads();
    if (threadIdx.x == 0) atomicAdd(meansum, sw[0] + sw[1] + sw[2] + sw[3]);
}

__global__ __launch_bounds__(256) void k_gip_accum(const float* __restrict__ Kb,
                                                   const float* __restrict__ diagv,
                                                   const float* __restrict__ meansum,
                                                   float* __restrict__ acc, int n, float gamma) {
    int tot = n * n;
    float invm = (float)n / meansum[0];   // 1/mean(diag)
    int stride = gridDim.x * blockDim.x;
    for (int idx = blockIdx.x * blockDim.x + threadIdx.x; idx < tot; idx += stride) {
        int i = idx / n, j = idx - i * n;
        float dist = (diagv[i] + diagv[j] - 2.f * Kb[idx]) * invm;
        acc[idx] += 0.25f * expf(-gamma * dist);
    }
}

__global__ void k_acc_init(float* __restrict__ acc, const float* __restrict__ sim, int tot4) {
    int idx = blockIdx.x * blockDim.x + threadIdx.x;
    int stride = gridDim.x * blockDim.x;
    for (; idx < tot4; idx += stride) {
        float4 v = ((const float4*)sim)[idx];
        v.x *= 0.25f; v.y *= 0.25f; v.z *= 0.25f; v.w *= 0.25f;
        ((float4*)acc)[idx] = v;
    }
}

// ---------------------------------------------------------------------------
// normalized_kernel pieces
// ---------------------------------------------------------------------------
__global__ __launch_bounds__(256) void k_norm_abs(float* __restrict__ Kc, float* __restrict__ dvec,
                                                  unsigned* __restrict__ minbits, int n) {
    int tot = n * n;
    float lmin = INFINITY;
    int stride = gridDim.x * blockDim.x;
    for (int idx = blockIdx.x * blockDim.x + threadIdx.x; idx < tot; idx += stride) {
        float v = fabsf(Kc[idx]);
        Kc[idx] = v;
        int i = idx / n, j = idx - i * n;
        if (i == j) dvec[i] = v;
        if (v > 0.f) lmin = fminf(lmin, v);
    }
    for (int o = 32; o; o >>= 1) lmin = fminf(lmin, __shfl_xor(lmin, o));
    __shared__ float sw[4];
    if ((threadIdx.x & 63) == 0) sw[threadIdx.x >> 6] = lmin;
    __syncthreads();
    if (threadIdx.x == 0) {
        float m = fminf(fminf(sw[0], sw[1]), fminf(sw[2], sw[3]));
        if (m < INFINITY) atomicMin(minbits, __float_as_uint(m));
    }
}

__global__ __launch_bounds__(256) void k_norm_div(float* __restrict__ Kc,
                                                  const float* __restrict__ dvec,
                                                  const unsigned* __restrict__ minbits, int n) {
    int tot = n * n;
    float mnz = __uint_as_float(*minbits);
    int stride = gridDim.x * blockDim.x;
    for (int idx = blockIdx.x * blockDim.x + threadIdx.x; idx < tot; idx += stride) {
        int j = idx % n;
        float v = Kc[idx];
        if (v == 0.f) v = mnz;
        Kc[idx] = v / dvec[j];
    }
}

// ---------------------------------------------------------------------------
// out[i,j] = 0.5 * (out[i,j] + T2[j,i]);  out: [DIS,SNO], T2: [SNO,DIS]
// ---------------------------------------------------------------------------
__global__ void k_combine(float* __restrict__ out, const float* __restrict__ T2) {
    __shared__ float tile[32][33];
    int i0 = blockIdx.y * 32;   // DIS dim
    int j0 = blockIdx.x * 32;   // SNO dim
    int tx = threadIdx.x, ty = threadIdx.y;
    #pragma unroll
    for (int k = 0; k < 32; k += 8) {
        int jj = j0 + ty + k, ii = i0 + tx;
        if (jj < kSNO && ii < kDIS) tile[ty + k][tx] = T2[(size_t)jj * kDIS + ii];
    }
    __syncthreads();
    #pragma unroll
    for (int k = 0; k < 32; k += 8) {
        int ii = i0 + ty + k, jj = j0 + tx;
        if (ii < kDIS && jj < kSNO) {
            size_t o = (size_t)ii * kSNO + jj;
            out[o] = 0.5f * (out[o] + tile[tx][ty + k]);
        }
    }
}

// ---------------------------------------------------------------------------
// Host-side launch
// ---------------------------------------------------------------------------
extern "C" void kernel_launch(void* const* d_in, const int* in_sizes, int n_in,
                              void* d_out, int out_size, void* d_ws, size_t ws_size,
                              hipStream_t stream) {
    const float* x       = (const float*)d_in[0];
    const float* adj     = (const float*)d_in[1];
    const int*   ei      = (const int*)d_in[2];
    const float* W1      = (const float*)d_in[3];
    const float* b1      = (const float*)d_in[4];
    const float* W2      = (const float*)d_in[5];
    const float* b2      = (const float*)d_in[6];
    const float* W3      = (const float*)d_in[7];
    const float* b3      = (const float*)d_in[8];
    const float* dis_sim = (const float*)d_in[9];
    const float* sno_sim = (const float*)d_in[10];
    const float* alpha1  = (const float*)d_in[11];
    const float* alpha2  = (const float*)d_in[12];
    const int* src = ei;
    const int* dst = ei + kE;
    float* out = (float*)d_out;

    // Workspace layout (floats). Total ~97.1M floats (~389 MB).
    float* ws = (float*)d_ws;
    size_t off = 0;
    auto alloc = [&](size_t n) { float* p = ws + off; off += n; return p; };
    float* wE    = alloc(kE);
    float* deg   = alloc(kN);
    float* dinv  = alloc(kN);
    float* H1    = alloc((size_t)kN * kF1);
    float* H2    = alloc((size_t)kN * kF2);
    float* H3    = alloc((size_t)kN * kF3);
    float* Htmp  = alloc((size_t)kN * kF1);
    float* Yn    = alloc((size_t)kSNO * kF1);
    float* Kbuf  = alloc((size_t)kSNO * kSNO);   // also reused for T2
    float* Nd    = alloc((size_t)kDIS * kDIS);
    float* Ns    = alloc((size_t)kSNO * kSNO);
    float* diagv = alloc(kSNO);                  // also reused as dvec
    float* meansum = alloc(1);
    unsigned* minbits = (unsigned*)alloc(1);
    (void)ws_size; (void)n_in; (void)in_sizes; (void)out_size;

    const int B = 256;

    // ---- edge prep
    k_init_deg<<<(kN + B - 1) / B, B, 0, stream>>>(deg);
    k_gather<<<(kE + B - 1) / B, B, 0, stream>>>(adj, src, dst, wE, deg);
    k_dinv<<<(kN + B - 1) / B, B, 0, stream>>>(deg, dinv);
    k_edgenorm<<<(kE + B - 1) / B, B, 0, stream>>>(wE, src, dst, dinv);

    // ---- GCN layers
    auto gcn = [&](const float* Hin, int Fin, const float* W, const float* b,
                   int Fout, float* Hout) {
        if (Fout >= 512) {
            dim3 g((Fout + 127) / 128, (kN + 127) / 128);
            k_sgemm<128, 128, 16, 8, 8, false><<<g, 256, 0, stream>>>(Hin, W, Htmp, kN, Fout, Fin);
        } else {
            dim3 g((Fout + 63) / 64, (kN + 63) / 64);
            k_sgemm<64, 64, 16, 4, 4, false><<<g, 256, 0, stream>>>(Hin, W, Htmp, kN, Fout, Fin);
        }
        int F4 = Fout / 4;
        k_selfloop<<<(kN * F4 + B - 1) / B, B, 0, stream>>>(Htmp, dinv, Hout, F4);
        k_scatter<<<(kE * F4 + B - 1) / B, B, 0, stream>>>(Htmp, Hout, src, dst, wE, F4);
        k_bias_relu<<<(kN * F4 + B - 1) / B, B, 0, stream>>>(Hout, b, F4);
    };
    gcn(x,  kN,  W1, b1, kF1, H1);
    gcn(H1, kF1, W2, b2, kF2, H2);
    gcn(H2, kF2, W3, b3, kF3, H3);

    // ---- GIP accumulation
    auto gip = [&](const float* H, int F, int rows, int rowoff, float gamma, float* acc) {
        k_rowminmax<<<rows, 256, 0, stream>>>(H + (size_t)rowoff * F, Yn, F);
        dim3 g((rows + 127) / 128, (rows + 127) / 128);
        k_sgemm<128, 128, 16, 8, 8, true><<<g, 256, 0, stream>>>(Yn, Yn, Kbuf, rows, rows, F);
        k_scal_init<<<1, 64, 0, stream>>>(meansum, minbits);
        k_diag_mean<<<12, 256, 0, stream>>>(Kbuf, diagv, meansum, rows);
        k_gip_accum<<<2048, 256, 0, stream>>>(Kbuf, diagv, meansum, acc, rows, gamma);
    };
    k_acc_init<<<2048, B, 0, stream>>>(Nd, dis_sim, kDIS * kDIS / 4);
    gip(H1, kF1, kDIS, 0, 0.5f, Nd);
    gip(H2, kF2, kDIS, 0, 0.5f, Nd);
    gip(H3, kF3, kDIS, 0, 0.5f, Nd);
    k_acc_init<<<2048, B, 0, stream>>>(Ns, sno_sim, kSNO * kSNO / 4);
    gip(H1, kF1, kSNO, kDIS, 0.5f, Ns);
    gip(H2, kF2, kSNO, kDIS, 0.5f, Ns);
    gip(H3, kF3, kSNO, kDIS, 0.5f, Ns);

    // ---- normalized_kernel (in place)
    auto normk = [&](float* Kc, int n) {
        k_scal_init<<<1, 64, 0, stream>>>(meansum, minbits);
        k_norm_abs<<<2048, B, 0, stream>>>(Kc, diagv, minbits, n);
        k_norm_div<<<2048, B, 0, stream>>>(Kc, diagv, minbits, n);
    };
    normk(Nd, kDIS);
    normk(Ns, kSNO);

    // ---- final: out = 0.5*(Nd@alpha1 + (Ns@alpha2)^T)
    {
        dim3 g1((kSNO + 127) / 128, (kDIS + 127) / 128);
        k_sgemm<128, 128, 16, 8, 8, false><<<g1, 256, 0, stream>>>(Nd, alpha1, out, kDIS, kSNO, kDIS);
        dim3 g2((kDIS + 127) / 128, (kSNO + 127) / 128);
        k_sgemm<128, 128, 16, 8, 8, false><<<g2, 256, 0, stream>>>(Ns, alpha2, Kbuf, kSNO, kDIS, kSNO);
        dim3 gc((kSNO + 31) / 32, (kDIS + 31) / 32);
        k_combine<<<gc, dim3(32, 8), 0, stream>>>(out, Kbuf);
    }
}